// Round 9
// baseline (286.783 us; speedup 1.0000x reference)
//
#include <hip/hip_runtime.h>
#include <hip/hip_bf16.h>
#include <type_traits>

#define TSEQ 2048
#define NBATCH 8
#define NROWS (NBATCH*TSEQ)   // 16384
#define EMB 128
#define NH 4
#define DH 32
#define OUTD 32
#define APLANE (NROWS*EMB)    // element offset between hi/lo planes (4 MB as bf16)
#define LOG2E 1.44269504088896340736f
#define NPAR 4                // split-K parity ways

typedef short s8v __attribute__((ext_vector_type(8)));
typedef short s4v __attribute__((ext_vector_type(4)));
typedef float f4v __attribute__((ext_vector_type(4)));
typedef float f16v __attribute__((ext_vector_type(16)));
typedef unsigned int u4v __attribute__((ext_vector_type(4)));

__device__ __forceinline__ unsigned short f2bf(float f){
  unsigned int u = __float_as_uint(f);
  unsigned int r = u + 0x7fffu + ((u >> 16) & 1u);
  return (unsigned short)(r >> 16);
}
__device__ __forceinline__ float bf2f(unsigned short u){
  return __uint_as_float(((unsigned int)u) << 16);
}
__device__ __forceinline__ float exp2fast(float x){
#if __has_builtin(__builtin_amdgcn_exp2f)
  return __builtin_amdgcn_exp2f(x);   // v_exp_f32 computes 2^x
#else
  return __expf(x * 0.6931471805599453f);
#endif
}

// ---------------- fused prep: xsplit (blocks 0..8191) + weight prep (rest) ----------------
struct WPack {
  const float* src[10];
  int off[10];     // fused hi-plane base (shorts)
  int ntk[10];     // NT*K of the fused matrix (lo at off+ntk)
  int rowoff[10];  // row offset of this source inside the fused matrix
  int nsh[10];     // log2(N) of source
  int kn[10];      // K*N of source
};
__global__ __launch_bounds__(256) void prep(WPack p, short* __restrict__ warena,
                                            const float* __restrict__ kq, const float* __restrict__ v,
                                            unsigned short* __restrict__ X){
  int blk = blockIdx.x;
  if (blk < (NROWS*EMB/256)){
    int idx = blk*256 + threadIdx.x;
    int row = idx >> 7, c = idx & 127;
    float val = (c < 64) ? kq[row*64 + c] : v[row*64 + (c-64)];
    unsigned short hi = f2bf(val);
    X[idx]          = hi;
    X[idx + APLANE] = f2bf(val - bf2f(hi));
    return;
  }
  blk -= (NROWS*EMB/256);
  int m = 0;
  #pragma unroll
  for (int i=0;i<10;i++){
    int nb = p.kn[i] >> 8;
    if (blk < nb){ m = i; break; }
    blk -= nb;
  }
  int idx = blk*256 + threadIdx.x;       // idx = k*N + n in source
  float x = p.src[m][idx];
  int nsh = p.nsh[m];
  int n = idx & ((1<<nsh)-1);
  int k = idx >> nsh;
  int K = p.kn[m] >> nsh;
  unsigned short hi = f2bf(x);
  unsigned short lo = f2bf(x - bf2f(hi));
  short* dh = warena + p.off[m] + (size_t)(p.rowoff[m] + n)*K + k;
  dh[0]        = (short)hi;
  dh[p.ntk[m]] = (short)lo;
}

// ---------------- pipelined MFMA GEMM, BN = NWV*16*CT, NWV waves, NITER k-steps ----------------
// C = scl * act(A @ W + bias). A bf16: dual-plane (aplane>0) or single (aplane=0).
// W arena [NT][K] bf16, hi at wt, lo at wt+NTK. BM=64, double-buffered LDS.
// W is register-double-buffered one iteration ahead (NITER compile-time, fully unrolled)
// so per-iteration L2 latency is hidden under the previous iteration's MFMAs.
// Optional fused V-transpose when the block's col span NB==128 covers [vcol0, vcol0+128).
struct GOuts {
  const float* bias[3];
  float* of[3];
  unsigned short* ob[3];
  float scl[3];
};
template<int CT, int NWV, int NITER>
__global__ __launch_bounds__(NWV*64) void gemm2(
    const unsigned short* __restrict__ A, int aplane, int lda, int K,
    const short* __restrict__ wt, int NTK,
    GOuts og, int NT, int nseg, int act,
    unsigned short* __restrict__ vtb, int vcol0){
  __shared__ short As[2][2][64*40];   // [buf][plane][r*40+c]; reused as Lt[c*72+t] for vtb
  const int tid  = threadIdx.x;
  const int w    = tid >> 6;
  const int lane = tid & 63;
  const int col  = lane & 15;
  const int quad = lane >> 4;
  const int row0 = blockIdx.x * 64;
  const int cb   = blockIdx.y*(NWV*16*CT) + w*(16*CT) + col;
  const bool two = (aplane != 0);

  f4v acc[4][CT];
  #pragma unroll
  for (int i=0;i<4;i++)
    #pragma unroll
    for (int j=0;j<CT;j++) acc[i][j] = (f4v){0.f,0.f,0.f,0.f};

  using sv = typename std::conditional<NWV==4, s8v, s4v>::type;
  const int ar = (NWV==4) ? (tid >> 2) : (tid >> 3);
  const int ac = (NWV==4) ? ((tid & 3)*8) : ((tid & 7)*4);
  const unsigned short* abase = A + (size_t)(row0 + ar)*lda;

  sv pah, pal;
  pah = *(const sv*)(abase + ac);
  if (two) pal = *(const sv*)(abase + aplane + ac);

  const short* wbase[CT];
  #pragma unroll
  for (int ct=0;ct<CT;ct++) wbase[ct] = wt + (size_t)(cb + ct*16)*K + quad*8;

  // preload W for iteration 0 (in flight during first stage+barrier)
  s8v wh[CT], wl[CT], wnh[CT], wnl[CT];
  #pragma unroll
  for (int ct=0;ct<CT;ct++){
    wh[ct] = *(const s8v*)(wbase[ct]);
    wl[ct] = *(const s8v*)(wbase[ct] + NTK);
  }

  #pragma unroll
  for (int i=0;i<NITER;i++){
    const int buf = i & 1;
    *(sv*)&As[buf][0][ar*40 + ac] = pah;
    if (two) *(sv*)&As[buf][1][ar*40 + ac] = pal;
    __syncthreads();
    if (i+1 < NITER){   // prefetch next A-tile + next W regs; latency overlaps MFMA below
      const int kcol = (i+1)*32 + ac;
      pah = *(const sv*)(abase + kcol);
      if (two) pal = *(const sv*)(abase + aplane + kcol);
      #pragma unroll
      for (int ct=0;ct<CT;ct++){
        wnh[ct] = *(const s8v*)(wbase[ct] + (i+1)*32);
        wnl[ct] = *(const s8v*)(wbase[ct] + (i+1)*32 + NTK);
      }
    }
    #pragma unroll
    for (int rt=0;rt<4;rt++){
      s8v ah = *(const s8v*)&As[buf][0][(rt*16 + col)*40 + quad*8];
      #pragma unroll
      for (int ct=0;ct<CT;ct++)
        acc[rt][ct] = __builtin_amdgcn_mfma_f32_16x16x32_bf16(ah, wh[ct], acc[rt][ct], 0, 0, 0);
      if (two){
        s8v al = *(const s8v*)&As[buf][1][(rt*16 + col)*40 + quad*8];
        #pragma unroll
        for (int ct=0;ct<CT;ct++)
          acc[rt][ct] = __builtin_amdgcn_mfma_f32_16x16x32_bf16(al, wh[ct], acc[rt][ct], 0, 0, 0);
      }
      #pragma unroll
      for (int ct=0;ct<CT;ct++)
        acc[rt][ct] = __builtin_amdgcn_mfma_f32_16x16x32_bf16(ah, wl[ct], acc[rt][ct], 0, 0, 0);
    }
    if (i+1 < NITER){
      #pragma unroll
      for (int ct=0;ct<CT;ct++){ wh[ct] = wnh[ct]; wl[ct] = wnl[ct]; }
    }
  }

  const int NB = NWV*16*CT;
  const int cb0 = (int)blockIdx.y * NB;
  const bool dotr = (NB == 128) && (vtb != nullptr) && (cb0 >= vcol0) && (cb0 < vcol0 + 128);
  short* Lt = &As[0][0][0];
  if (dotr) __syncthreads();   // all waves done reading As before restage

  #pragma unroll
  for (int ct=0;ct<CT;ct++){
    const int cg = cb + ct*16;
    int seg, lcol, ldc;
    if (nseg > 1){ seg = cg >> 7; lcol = cg & 127; ldc = 128; }
    else         { seg = 0; lcol = cg; ldc = NT; }
    const float bv = og.bias[seg][lcol];
    const float sc = og.scl[seg];
    float* of = og.of[seg];
    unsigned short* ob = og.ob[seg];
    #pragma unroll
    for (int rt=0;rt<4;rt++){
      s4v pk;
      #pragma unroll
      for (int r=0;r<4;r++){
        const int row = row0 + rt*16 + quad*4 + r;
        float val = acc[rt][ct][r] + bv;
        if (act == 1) val = 0.5f*val*(1.f + erff(val*0.70710678118654752440f));
        val *= sc;
        if (ob)      ob[(size_t)row*ldc + lcol] = f2bf(val);
        else if (of) of[(size_t)row*ldc + lcol] = val;
        if (dotr) pk[r] = (short)f2bf(val);
      }
      if (dotr)
        *(s4v*)&Lt[((cg - cb0))*72 + rt*16 + quad*4] = pk;
    }
  }
  if (dotr){
    __syncthreads();
    const int b = row0 >> 11, t0 = row0 & 2047;
    #pragma unroll
    for (int it=0; it<2*CT; it++){
      const int cl = it*(NWV*8) + (tid>>3);
      const int t8 = (tid&7)*8;
      s8v o = *(const s8v*)&Lt[cl*72 + t8];
      const int cr = cb0 + cl - vcol0;      // 0..127 within V
      *(s8v*)(vtb + ((size_t)((b*4 + (cr>>5))*32 + (cr&31)))*2048 + t0 + t8) = o;
    }
  }
}

// ---------------- fused F2 GEMM: [N x 512] @ [512 x 128] + epilogue ----------------
// 512 thr = 8 waves, each block owns 64 rows x ALL 128 cols (full row -> can fuse row ops).
// MODE 0: + residual(h1p) + LayerNorm -> vAp dual-plane
// MODE 1: + output head (tile @ Wo + bo) -> out
template<int MODE>
__global__ __launch_bounds__(512) void gemm_f2(
    const unsigned short* __restrict__ A,    // mid bf16, lda=512, single plane
    const short* __restrict__ wt, int NTK,   // dual-plane W [128][512]
    const float* __restrict__ bias,          // f2b [128]
    const unsigned short* __restrict__ resid,// MODE0: h1p dual-plane
    const float* __restrict__ g, const float* __restrict__ bt,
    unsigned short* __restrict__ outp,       // MODE0: vAp dual-plane
    const float* __restrict__ Wo, const float* __restrict__ bo,
    float* __restrict__ outhead){            // MODE1: out [N x 32]
  __shared__ short As[2][64*40];
  __shared__ float Lf[64*132];
  __shared__ float Ws2[128*32];
  const int tid  = threadIdx.x;
  const int w    = tid >> 6;
  const int lane = tid & 63;
  const int col  = lane & 15;
  const int quad = lane >> 4;
  const int row0 = blockIdx.x * 64;
  const int cg   = w*16 + col;            // 0..127

  if (MODE == 1){
    for (int idx = tid; idx < 128*32; idx += 512) Ws2[idx] = Wo[idx];
  }

  f4v acc[4];
  #pragma unroll
  for (int i=0;i<4;i++) acc[i] = (f4v){0.f,0.f,0.f,0.f};

  const int ar = tid >> 3, ac = (tid & 7)*4;
  const unsigned short* abase = A + (size_t)(row0 + ar)*512;
  s4v pa = *(const s4v*)(abase + ac);
  const short* wb = wt + (size_t)cg*512 + quad*8;

  for (int i=0;i<16;i++){
    const int buf = i & 1;
    *(s4v*)&As[buf][ar*40 + ac] = pa;
    __syncthreads();
    if (i+1 < 16) pa = *(const s4v*)(abase + (i+1)*32 + ac);
    s8v bh = *(const s8v*)(wb + i*32);
    s8v bl = *(const s8v*)(wb + i*32 + NTK);
    #pragma unroll
    for (int rt=0;rt<4;rt++){
      s8v ah = *(const s8v*)&As[buf][(rt*16 + col)*40 + quad*8];
      acc[rt] = __builtin_amdgcn_mfma_f32_16x16x32_bf16(ah, bh, acc[rt], 0, 0, 0);
      acc[rt] = __builtin_amdgcn_mfma_f32_16x16x32_bf16(ah, bl, acc[rt], 0, 0, 0);
    }
  }

  // stage tile (with bias) to LDS
  const float bv = bias[cg];
  #pragma unroll
  for (int rt=0;rt<4;rt++){
    #pragma unroll
    for (int r=0;r<4;r++){
      const int row = rt*16 + quad*4 + r;
      Lf[row*132 + cg] = acc[rt][r] + bv;
    }
  }
  __syncthreads();

  if (MODE == 0){
    // residual + LayerNorm, 8 rows per wave
    for (int rr=0; rr<8; rr++){
      const int row = w*8 + rr;
      const size_t gbase = (size_t)(row0 + row)*EMB;
      float x0 = Lf[row*132 + lane]
               + bf2f(resid[gbase+lane])    + bf2f(resid[gbase+lane+APLANE]);
      float x1 = Lf[row*132 + lane + 64]
               + bf2f(resid[gbase+lane+64]) + bf2f(resid[gbase+lane+64+APLANE]);
      float s  = x0 + x1;
      float s2 = x0*x0 + x1*x1;
      #pragma unroll
      for (int off=1; off<64; off<<=1){
        s  += __shfl_xor(s,  off);
        s2 += __shfl_xor(s2, off);
      }
      float mean = s * (1.f/128.f);
      float var  = s2 * (1.f/128.f) - mean*mean;
      float rstd = rsqrtf(var + 1e-5f);
      float y0 = (x0-mean)*rstd*g[lane]    + bt[lane];
      float y1 = (x1-mean)*rstd*g[lane+64] + bt[lane+64];
      unsigned short h0b = f2bf(y0), h1b = f2bf(y1);
      outp[gbase+lane]             = h0b;
      outp[gbase+lane+64]          = h1b;
      outp[gbase+lane+APLANE]      = f2bf(y0 - bf2f(h0b));
      outp[gbase+lane+64+APLANE]   = f2bf(y1 - bf2f(h1b));
    }
  } else {
    // output head: out[row, c] = sum_k Lf[row][k] * Wo[k][c] + bo[c]
    const int row = tid >> 3, c0 = (tid & 7)*4;
    f4v a4;
    #pragma unroll
    for (int j=0;j<4;j++) a4[j] = bo[c0+j];
    #pragma unroll 16
    for (int k=0;k<128;k++){
      const float av = Lf[row*132 + k];
      #pragma unroll
      for (int j=0;j<4;j++) a4[j] = fmaf(av, Ws2[k*32 + c0 + j], a4[j]);
    }
    float* op = outhead + (size_t)(row0 + row)*OUTD + c0;
    #pragma unroll
    for (int j=0;j<4;j++) op[j] = a4[j];
  }
}

// ---------------- flash attention v5: 32x32 MFMA, swapped QK^T, in-register softmax->PV ----------------
#define KSTR 40
#define VSTR 72
__device__ __forceinline__ int kswz(int row, int c){ return (row*KSTR + c) ^ (((row>>3)&3)<<3); }
__device__ __forceinline__ int vswz(int row, int c){ return (row*VSTR + c) ^ (((row>>3)&3)<<3); }

__global__ __launch_bounds__(256, 4) void flash5(const unsigned short* __restrict__ Qb,
                                                 const unsigned short* __restrict__ Kb,
                                                 const unsigned short* __restrict__ Vtb,
                                                 float* __restrict__ O, float* __restrict__ L,
                                                 int mode){
  __shared__ short Kt[64*KSTR];
  __shared__ short Vt[32*VSTR];
  const int tid  = threadIdx.x;
  const int w    = tid >> 6;
  const int lane = tid & 63;
  const int q31  = lane & 31;
  const int hi   = lane >> 5;
  const int bh = blockIdx.y;
  const int b = bh >> 2, h = bh & 3;
  const int par = blockIdx.z;
  float* Op = O + (size_t)par*NROWS*EMB;
  float* Lp = L + (size_t)par*NROWS*NH;
  const int kr = tid >> 2, kc8 = (tid & 3)*8;   // K staging: 64 rows x 32 d
  const int vd = tid >> 3, vk8 = (tid & 7)*8;   // V staging: 32 d x 64 k

  for (int pass = 0; pass < 2; pass++){
    const int qt = pass ? (int)blockIdx.x : (15 - (int)blockIdx.x);  // heavy first
    const int qbase = qt*128;
    const int qrow  = qbase + w*32 + q31;
    const int jtmax = 2*qt + 1;

    s8v qB0 = *(const s8v*)(Qb + (size_t)(b*TSEQ + qrow)*EMB + h*DH + hi*8);
    s8v qB1 = *(const s8v*)(Qb + (size_t)(b*TSEQ + qrow)*EMB + h*DH + 16 + hi*8);
    f16v o;
    #pragma unroll
    for (int r=0;r<16;r++) o[r] = 0.f;
    float lr = 0.f;

    if (par <= jtmax){
      s8v ka = *(const s8v*)(Kb + (size_t)(b*TSEQ + par*64 + kr)*EMB + h*DH + kc8);
      s8v va = *(const s8v*)(Vtb + ((size_t)bh*32 + vd)*TSEQ + par*64 + vk8);
      for (int jt = par; jt <= jtmax; jt += NPAR){
        __syncthreads();
        *(s8v*)&Kt[kswz(kr, kc8)] = ka;
        *(s8v*)&Vt[vswz(vd, vk8)] = va;
        __syncthreads();
        if (jt + NPAR <= jtmax){
          ka = *(const s8v*)(Kb + (size_t)(b*TSEQ + (jt+NPAR)*64 + kr)*EMB + h*DH + kc8);
          va = *(const s8v*)(Vtb + ((size_t)bh*32 + vd)*TSEQ + (jt+NPAR)*64 + vk8);
        }
        const bool domask = (jt >= 2*qt);
        #pragma unroll
        for (int kt=0;kt<2;kt++){
          f16v s;
          #pragma unroll
          for (int r=0;r<16;r++) s[r] = 0.f;
          {
            s8v kf0 = *(const s8v*)&Kt[kswz(kt*32 + q31, hi*8)];
            s = __builtin_amdgcn_mfma_f32_32x32x16_bf16(kf0, qB0, s, 0, 0, 0);
            s8v kf1 = *(const s8v*)&Kt[kswz(kt*32 + q31, 16 + hi*8)];
            s = __builtin_amdgcn_mfma_f32_32x32x16_bf16(kf1, qB1, s, 0, 0, 0);
          }
          if (domask){
            #pragma unroll
            for (int r=0;r<16;r++){
              const int jg = jt*64 + kt*32 + (r&3) + 8*(r>>2) + 4*hi;
              const bool ok = (mode==0) ? (jg <= qrow) : ((jg < qrow) || (qrow==0 && jg==0));
              s[r] = ok ? s[r] : -1e30f;
            }
          }
          #pragma unroll
          for (int r=0;r<16;r++){ float pv = exp2fast(s[r]); s[r] = pv; lr += pv; }
          unsigned P2[4][2];
          #pragma unroll
          for (int m=0;m<4;m++){
            asm("v_cvt_pk_bf16_f32 %0, %1, %2" : "=v"(P2[m][0]) : "v"(s[4*m+0]), "v"(s[4*m+1]));
            asm("v_cvt_pk_bf16_f32 %0, %1, %2" : "=v"(P2[m][1]) : "v"(s[4*m+2]), "v"(s[4*m+3]));
          }
          #pragma unroll
          for (int kcl=0;kcl<2;kcl++){
            const unsigned own0 = hi ? P2[2*kcl+1][0] : P2[2*kcl][0];
            const unsigned own1 = hi ? P2[2*kcl+1][1] : P2[2*kcl][1];
            const unsigned inv0 = hi ? P2[2*kcl][0]   : P2[2*kcl+1][0];
            const unsigned inv1 = hi ? P2[2*kcl][1]   : P2[2*kcl+1][1];
            const unsigned sx0 = (unsigned)__shfl_xor((int)inv0, 32);
            const unsigned sx1 = (unsigned)__shfl_xor((int)inv1, 32);
            u4v au;
            au[0] = hi ? sx0 : own0;  au[1] = hi ? sx1 : own1;
            au[2] = hi ? own0 : sx0;  au[3] = hi ? own1 : sx1;
            s8v af = __builtin_bit_cast(s8v, au);
            s8v vf = *(const s8v*)&Vt[vswz(q31, kt*32 + kcl*16 + hi*8)];
            o = __builtin_amdgcn_mfma_f32_32x32x16_bf16(af, vf, o, 0, 0, 0);
          }
        }
      }
    }
    const float lt = lr + __shfl_xor(lr, 32);
    #pragma unroll
    for (int r=0;r<16;r++){
      const int ql = (r&3) + 8*(r>>2) + 4*hi;
      Op[(size_t)(b*TSEQ + qbase + w*32 + ql)*EMB + h*DH + q31] = o[r];
    }
    if (hi == 0) Lp[(size_t)(b*TSEQ + qrow)*NH + h] = lt;
  }
}

// ---------------- combine + residual + LayerNorm (layer A) -> dual-plane bf16 ----------------
__global__ __launch_bounds__(256) void combine_ln(const float* __restrict__ O, const float* __restrict__ L,
                                                  const float* __restrict__ Vf,
                                                  const float* __restrict__ g, const float* __restrict__ bt,
                                                  unsigned short* __restrict__ outp){
  const int row = blockIdx.x*4 + (threadIdx.x >> 6);
  const int tid = threadIdx.x & 63;
  const size_t base = (size_t)row*EMB;
  const int h0 = tid >> 5, h1i = 2 + (tid >> 5);
  float la = 0.f, lb = 0.f, s0 = 0.f, s1 = 0.f;
  #pragma unroll
  for (int p=0;p<NPAR;p++){
    la += L[(size_t)p*NROWS*NH + (size_t)row*NH + h0];
    lb += L[(size_t)p*NROWS*NH + (size_t)row*NH + h1i];
    s0 += O[(size_t)p*NROWS*EMB + base + tid];
    s1 += O[(size_t)p*NROWS*EMB + base + tid + 64];
  }
  float x0 = Vf[base+tid]    + s0/la;
  float x1 = Vf[base+tid+64] + s1/lb;
  float s  = x0 + x1;
  float s2 = x0*x0 + x1*x1;
  #pragma unroll
  for (int off=1; off<64; off<<=1){
    s  += __shfl_xor(s,  off);
    s2 += __shfl_xor(s2, off);
  }
  float mean = s * (1.f/128.f);
  float var  = s2 * (1.f/128.f) - mean*mean;
  float rstd = rsqrtf(var + 1e-5f);
  float y0 = (x0-mean)*rstd*g[tid]    + bt[tid];
  float y1 = (x1-mean)*rstd*g[tid+64] + bt[tid+64];
  unsigned short h0b = f2bf(y0), h1b = f2bf(y1);
  outp[base+tid]             = h0b;
  outp[base+tid+64]          = h1b;
  outp[base+tid+APLANE]      = f2bf(y0 - bf2f(h0b));
  outp[base+tid+64+APLANE]   = f2bf(y1 - bf2f(h1b));
}

// ---------------- combine (layer B): normalize -> dual-plane bf16 ----------------
__global__ __launch_bounds__(256) void combine_b(const float* __restrict__ O, const float* __restrict__ L,
                                                 unsigned short* __restrict__ outp){
  const int idx = blockIdx.x*256 + threadIdx.x;
  const int row = idx >> 7, c = idx & 127, h = c >> 5;
  float l = 0.f, ov = 0.f;
  #pragma unroll
  for (int p=0;p<NPAR;p++){
    l  += L[(size_t)p*NROWS*NH + (size_t)row*NH + h];
    ov += O[(size_t)p*NROWS*EMB + idx];
  }
  const float v = ov / l;
  unsigned short hb = f2bf(v);
  outp[idx]          = hb;
  outp[idx + APLANE] = f2bf(v - bf2f(hb));
}

extern "C" void kernel_launch(void* const* d_in, const int* in_sizes, int n_in,
                              void* d_out, int out_size, void* d_ws, size_t ws_size,
                              hipStream_t stream) {
  const float* kq    = (const float*)d_in[0];
  const float* v     = (const float*)d_in[1];
  const float* A_Wk  = (const float*)d_in[2];  const float* A_bk  = (const float*)d_in[3];
  const float* A_Wq  = (const float*)d_in[4];  const float* A_bq  = (const float*)d_in[5];
  const float* A_Wv  = (const float*)d_in[6];  const float* A_bv  = (const float*)d_in[7];
  const float* A_f1W = (const float*)d_in[8];  const float* A_f1b = (const float*)d_in[9];
  const float* A_f2W = (const float*)d_in[10]; const float* A_f2b = (const float*)d_in[11];
  const float* A_n1g = (const float*)d_in[12]; const float* A_n1b = (const float*)d_in[13];
  const float* A_n2g = (const float*)d_in[14]; const float* A_n2b = (const float*)d_in[15];
  const float* B_Wk  = (const float*)d_in[16]; const float* B_bk  = (const float*)d_in[17];
  const float* B_Wq  = (const float*)d_in[18]; const float* B_bq  = (const float*)d_in[19];
  const float* B_Wv  = (const float*)d_in[20]; const float* B_bv  = (const float*)d_in[21];
  const float* B_f1W = (const float*)d_in[22]; const float* B_f1b = (const float*)d_in[23];
  const float* B_f2W = (const float*)d_in[24]; const float* B_f2b = (const float*)d_in[25];
  const float* out_W = (const float*)d_in[26]; const float* out_b = (const float*)d_in[27];
  float* out = (float*)d_out;
  (void)in_sizes; (void)n_in; (void)out_size; (void)ws_size;

  char* ws = (char*)d_ws;
  const size_t MB = 1024*1024;
  short* warena = (short*)ws;                              // 0-2 MB (1.32 MB used)
  unsigned short* Xs  = (unsigned short*)(ws + 2*MB);      // 2-10: X dual-plane bf16
  unsigned short* Qbf = (unsigned short*)(ws + 10*MB);     // 10-14
  unsigned short* Kbf = (unsigned short*)(ws + 14*MB);     // 14-18
  unsigned short* Vtb = (unsigned short*)(ws + 18*MB);     // 18-22
  float* Vf  = (float*)(ws + 22*MB);                       // 22-30
  float* Opar = (float*)(ws + 30*MB);                      // 30-62: 4 x 8MB split-K partial O
  float* Lpar = (float*)(ws + 62*MB);                      // 62-66: 4 x 1MB (256KB used) partial L
  unsigned short* h1p = (unsigned short*)(ws + 66*MB);     // 66-74: h1 dual-plane / attnB dual-plane
  unsigned short* mid = (unsigned short*)(ws + 74*MB);     // 74-90: bf16 [N x 512]
  unsigned short* vAp = (unsigned short*)(ws + 90*MB);     // 90-98: vA dual-plane

  // ---- fused prep: xsplit + weight prep ----
  WPack p;
  const float* srcs[10] = {A_Wq,A_Wk,A_Wv,A_f1W,A_f2W,B_Wq,B_Wk,B_Wv,B_f1W,B_f2W};
  int kn[10]     = {16384,16384,16384,65536,65536,8192,8192,16384,65536,65536};
  int nsh[10]    = {7,7,7,9,7,7,7,7,9,7};
  int off[10]    = {0,0,0,98304,229376,360448,360448,393216,425984,557056};
  int ntk[10]    = {49152,49152,49152,65536,65536,16384,16384,16384,65536,65536};
  int rowoff[10] = {0,128,256,0,0,0,128,0,0,0};
  int nblk = 0;
  for (int i=0;i<10;i++){
    p.src[i]=srcs[i]; p.kn[i]=kn[i]; p.nsh[i]=nsh[i];
    p.off[i]=off[i]; p.ntk[i]=ntk[i]; p.rowoff[i]=rowoff[i];
    nblk += kn[i] >> 8;
  }
  prep<<<(NROWS*EMB/256) + nblk, 256, 0, stream>>>(p, warena, kq, v, Xs);

  GOuts oQKVA = {{A_bq,A_bk,A_bv},{nullptr,nullptr,Vf},{Qbf,Kbf,nullptr},{LOG2E,1.f,1.f}};
  GOuts oF1A  = {{A_f1b,nullptr,nullptr},{nullptr,nullptr,nullptr},{mid,nullptr,nullptr},{1.f,1.f,1.f}};
  GOuts oQKB  = {{B_bq,B_bk,nullptr},{nullptr,nullptr,nullptr},{Qbf,Kbf,nullptr},{LOG2E,1.f,1.f}};
  GOuts oVB   = {{B_bv,nullptr,nullptr},{nullptr,nullptr,nullptr},{nullptr,nullptr,nullptr},{1.f,1.f,1.f}};
  GOuts oF1B  = {{B_f1b,nullptr,nullptr},{nullptr,nullptr,nullptr},{mid,nullptr,nullptr},{1.f,1.f,1.f}};

  // ---- Layer A ----
  gemm2<2,4,4><<<dim3(256,3), 256, 0, stream>>>(Xs, APLANE, 128, 128, warena + 0, 49152, oQKVA, 384, 3, 0, Vtb, 256);
  flash5<<<dim3(8,32,NPAR), 256, 0, stream>>>(Qbf, Kbf, Vtb, Opar, Lpar, 0);
  combine_ln<<<NROWS/4, 256, 0, stream>>>(Opar, Lpar, Vf, A_n1g, A_n1b, h1p);
  gemm2<2,8,4><<<dim3(256,2), 512, 0, stream>>>(h1p, APLANE, 128, 128, warena + 98304, 65536, oF1A, 512, 1, 1, nullptr, 0);
  gemm_f2<0><<<256, 512, 0, stream>>>(mid, warena + 229376, 65536, A_f2b,
                                      h1p, A_n2g, A_n2b, vAp, nullptr, nullptr, nullptr);

  // ---- Layer B ----
  gemm2<2,8,2><<<dim3(256,1), 512, 0, stream>>>(Xs, APLANE, 128, 64, warena + 360448, 16384, oQKB, 256, 2, 0, nullptr, 0);
  gemm2<1,8,4><<<dim3(256,1), 512, 0, stream>>>(vAp, APLANE, 128, 128, warena + 393216, 16384, oVB, 128, 1, 0, Vtb, 0);
  flash5<<<dim3(8,32,NPAR), 256, 0, stream>>>(Qbf, Kbf, Vtb, Opar, Lpar, 1);
  combine_b<<<NROWS*128/256, 256, 0, stream>>>(Opar, Lpar, h1p);
  gemm2<2,8,4><<<dim3(256,2), 512, 0, stream>>>(h1p, APLANE, 128, 128, warena + 425984, 65536, oF1B, 512, 1, 1, nullptr, 0);
  gemm_f2<1><<<256, 512, 0, stream>>>(mid, warena + 557056, 65536, B_f2b,
                                      nullptr, nullptr, nullptr, nullptr, out_W, out_b, out);
}

// Round 10
// 272.495 us; speedup vs baseline: 1.0524x; 1.0524x over previous
//
#include <hip/hip_runtime.h>
#include <hip/hip_bf16.h>
#include <type_traits>

#define TSEQ 2048
#define NBATCH 8
#define NROWS (NBATCH*TSEQ)   // 16384
#define EMB 128
#define NH 4
#define DH 32
#define OUTD 32
#define APLANE (NROWS*EMB)    // element offset between hi/lo planes (4 MB as bf16)
#define LOG2E 1.44269504088896340736f
#define NPAR 4                // split-K parity ways

typedef short s8v __attribute__((ext_vector_type(8)));
typedef short s4v __attribute__((ext_vector_type(4)));
typedef float f4v __attribute__((ext_vector_type(4)));
typedef float f16v __attribute__((ext_vector_type(16)));
typedef unsigned int u4v __attribute__((ext_vector_type(4)));

__device__ __forceinline__ unsigned short f2bf(float f){
  unsigned int u = __float_as_uint(f);
  unsigned int r = u + 0x7fffu + ((u >> 16) & 1u);
  return (unsigned short)(r >> 16);
}
__device__ __forceinline__ float bf2f(unsigned short u){
  return __uint_as_float(((unsigned int)u) << 16);
}
__device__ __forceinline__ float exp2fast(float x){
#if __has_builtin(__builtin_amdgcn_exp2f)
  return __builtin_amdgcn_exp2f(x);   // v_exp_f32 computes 2^x
#else
  return __expf(x * 0.6931471805599453f);
#endif
}

// ---------------- fused prep: xsplit (blocks 0..8191) + weight prep (rest) ----------------
struct WPack {
  const float* src[10];
  int off[10];     // fused hi-plane base (shorts)
  int ntk[10];     // NT*K of the fused matrix (lo at off+ntk)
  int rowoff[10];  // row offset of this source inside the fused matrix
  int nsh[10];     // log2(N) of source
  int kn[10];      // K*N of source
};
__global__ __launch_bounds__(256) void prep(WPack p, short* __restrict__ warena,
                                            const float* __restrict__ kq, const float* __restrict__ v,
                                            unsigned short* __restrict__ X){
  int blk = blockIdx.x;
  if (blk < (NROWS*EMB/256)){
    int idx = blk*256 + threadIdx.x;
    int row = idx >> 7, c = idx & 127;
    float val = (c < 64) ? kq[row*64 + c] : v[row*64 + (c-64)];
    unsigned short hi = f2bf(val);
    X[idx]          = hi;
    X[idx + APLANE] = f2bf(val - bf2f(hi));
    return;
  }
  blk -= (NROWS*EMB/256);
  int m = 0;
  #pragma unroll
  for (int i=0;i<10;i++){
    int nb = p.kn[i] >> 8;
    if (blk < nb){ m = i; break; }
    blk -= nb;
  }
  int idx = blk*256 + threadIdx.x;       // idx = k*N + n in source
  float x = p.src[m][idx];
  int nsh = p.nsh[m];
  int n = idx & ((1<<nsh)-1);
  int k = idx >> nsh;
  int K = p.kn[m] >> nsh;
  unsigned short hi = f2bf(x);
  unsigned short lo = f2bf(x - bf2f(hi));
  short* dh = warena + p.off[m] + (size_t)(p.rowoff[m] + n)*K + k;
  dh[0]        = (short)hi;
  dh[p.ntk[m]] = (short)lo;
}

// ---------------- pipelined MFMA GEMM, BN = NWV*16*CT, NWV waves, NITER k-steps ----------------
// C = scl * act(A @ W + bias). A bf16: dual-plane (aplane>0) or single (aplane=0).
// W arena [NT][K] bf16, hi at wt, lo at wt+NTK. BM=64, double-buffered LDS.
// W register-double-buffered one iteration ahead (NITER compile-time, fully unrolled).
// CB mode (layer B F1): A-staging computes the split-K combine on the fly
//   x = SUM_p cbO[p] / SUM_p cbL[p]  (head index == k-iteration since 32 cols/head),
// packs to hi/lo bf16, writes both LDS planes -- combine_b kernel + h1p round-trip eliminated.
// Optional fused V-transpose when the block's col span NB==128 covers [vcol0, vcol0+128).
struct GOuts {
  const float* bias[3];
  float* of[3];
  unsigned short* ob[3];
  float scl[3];
};
template<int CT, int NWV, int NITER, int CB>
__global__ __launch_bounds__(NWV*64) void gemm2(
    const unsigned short* __restrict__ A, int aplane, int lda, int K,
    const short* __restrict__ wt, int NTK,
    GOuts og, int NT, int nseg, int act,
    unsigned short* __restrict__ vtb, int vcol0,
    const float* __restrict__ cbO, const float* __restrict__ cbL){
  __shared__ short As[2][2][64*40];   // [buf][plane][r*40+c]; reused as Lt[c*72+t] for vtb
  const int tid  = threadIdx.x;
  const int w    = tid >> 6;
  const int lane = tid & 63;
  const int col  = lane & 15;
  const int quad = lane >> 4;
  const int row0 = blockIdx.x * 64;
  const int cb   = blockIdx.y*(NWV*16*CT) + w*(16*CT) + col;
  const bool two = CB ? true : (aplane != 0);

  f4v acc[4][CT];
  #pragma unroll
  for (int i=0;i<4;i++)
    #pragma unroll
    for (int j=0;j<CT;j++) acc[i][j] = (f4v){0.f,0.f,0.f,0.f};

  using sv = typename std::conditional<NWV==4, s8v, s4v>::type;
  const int ar = (NWV==4) ? (tid >> 2) : (tid >> 3);
  const int ac = (NWV==4) ? ((tid & 3)*8) : ((tid & 7)*4);

  const unsigned short* abase = nullptr;
  sv pah, pal;
  float4 cnx[NPAR]; float cnl[NPAR];
  if constexpr (CB){
    #pragma unroll
    for (int p2=0;p2<NPAR;p2++){
      cnx[p2] = *(const float4*)(cbO + (size_t)p2*NROWS*EMB + (size_t)(row0+ar)*EMB + ac);
      cnl[p2] = cbL[(size_t)p2*NROWS*NH + (size_t)(row0+ar)*NH + 0];
    }
  } else {
    abase = A + (size_t)(row0 + ar)*lda;
    pah = *(const sv*)(abase + ac);
    if (two) pal = *(const sv*)(abase + aplane + ac);
  }

  const short* wbase[CT];
  #pragma unroll
  for (int ct=0;ct<CT;ct++) wbase[ct] = wt + (size_t)(cb + ct*16)*K + quad*8;

  // preload W for iteration 0 (in flight during first stage+barrier)
  s8v wh[CT], wl[CT], wnh[CT], wnl[CT];
  #pragma unroll
  for (int ct=0;ct<CT;ct++){
    wh[ct] = *(const s8v*)(wbase[ct]);
    wl[ct] = *(const s8v*)(wbase[ct] + NTK);
  }

  #pragma unroll
  for (int i=0;i<NITER;i++){
    const int buf = i & 1;
    if constexpr (CB){
      float sx=0.f, sy=0.f, sz=0.f, sw=0.f, ls=0.f;
      #pragma unroll
      for (int p2=0;p2<NPAR;p2++){
        sx += cnx[p2].x; sy += cnx[p2].y; sz += cnx[p2].z; sw += cnx[p2].w;
        ls += cnl[p2];
      }
      const float linv = 1.f/ls;
      float xs[4] = {sx*linv, sy*linv, sz*linv, sw*linv};
      s4v ph, pl;
      #pragma unroll
      for (int j=0;j<4;j++){
        unsigned short hb = f2bf(xs[j]);
        ph[j] = (short)hb;
        pl[j] = (short)f2bf(xs[j] - bf2f(hb));
      }
      *(s4v*)&As[buf][0][ar*40 + ac] = ph;
      *(s4v*)&As[buf][1][ar*40 + ac] = pl;
    } else {
      *(sv*)&As[buf][0][ar*40 + ac] = pah;
      if (two) *(sv*)&As[buf][1][ar*40 + ac] = pal;
    }
    __syncthreads();
    if (i+1 < NITER){   // prefetch next A/combine data + next W regs; overlaps MFMA below
      if constexpr (CB){
        #pragma unroll
        for (int p2=0;p2<NPAR;p2++){
          cnx[p2] = *(const float4*)(cbO + (size_t)p2*NROWS*EMB + (size_t)(row0+ar)*EMB + (i+1)*32 + ac);
          cnl[p2] = cbL[(size_t)p2*NROWS*NH + (size_t)(row0+ar)*NH + (i+1)];
        }
      } else {
        const int kcol = (i+1)*32 + ac;
        pah = *(const sv*)(abase + kcol);
        if (two) pal = *(const sv*)(abase + aplane + kcol);
      }
      #pragma unroll
      for (int ct=0;ct<CT;ct++){
        wnh[ct] = *(const s8v*)(wbase[ct] + (i+1)*32);
        wnl[ct] = *(const s8v*)(wbase[ct] + (i+1)*32 + NTK);
      }
    }
    #pragma unroll
    for (int rt=0;rt<4;rt++){
      s8v ah = *(const s8v*)&As[buf][0][(rt*16 + col)*40 + quad*8];
      #pragma unroll
      for (int ct=0;ct<CT;ct++)
        acc[rt][ct] = __builtin_amdgcn_mfma_f32_16x16x32_bf16(ah, wh[ct], acc[rt][ct], 0, 0, 0);
      if (two){
        s8v al = *(const s8v*)&As[buf][1][(rt*16 + col)*40 + quad*8];
        #pragma unroll
        for (int ct=0;ct<CT;ct++)
          acc[rt][ct] = __builtin_amdgcn_mfma_f32_16x16x32_bf16(al, wh[ct], acc[rt][ct], 0, 0, 0);
      }
      #pragma unroll
      for (int ct=0;ct<CT;ct++)
        acc[rt][ct] = __builtin_amdgcn_mfma_f32_16x16x32_bf16(ah, wl[ct], acc[rt][ct], 0, 0, 0);
    }
    if (i+1 < NITER){
      #pragma unroll
      for (int ct=0;ct<CT;ct++){ wh[ct] = wnh[ct]; wl[ct] = wnl[ct]; }
    }
  }

  const int NB = NWV*16*CT;
  const int cb0 = (int)blockIdx.y * NB;
  const bool dotr = (NB == 128) && (vtb != nullptr) && (cb0 >= vcol0) && (cb0 < vcol0 + 128);
  short* Lt = &As[0][0][0];
  if (dotr) __syncthreads();   // all waves done reading As before restage

  #pragma unroll
  for (int ct=0;ct<CT;ct++){
    const int cg = cb + ct*16;
    int seg, lcol, ldc;
    if (nseg > 1){ seg = cg >> 7; lcol = cg & 127; ldc = 128; }
    else         { seg = 0; lcol = cg; ldc = NT; }
    const float bv = og.bias[seg][lcol];
    const float sc = og.scl[seg];
    float* of = og.of[seg];
    unsigned short* ob = og.ob[seg];
    #pragma unroll
    for (int rt=0;rt<4;rt++){
      s4v pk;
      #pragma unroll
      for (int r=0;r<4;r++){
        const int row = row0 + rt*16 + quad*4 + r;
        float val = acc[rt][ct][r] + bv;
        if (act == 1) val = 0.5f*val*(1.f + erff(val*0.70710678118654752440f));
        val *= sc;
        if (ob)      ob[(size_t)row*ldc + lcol] = f2bf(val);
        else if (of) of[(size_t)row*ldc + lcol] = val;
        if (dotr) pk[r] = (short)f2bf(val);
      }
      if (dotr)
        *(s4v*)&Lt[((cg - cb0))*72 + rt*16 + quad*4] = pk;
    }
  }
  if (dotr){
    __syncthreads();
    const int b = row0 >> 11, t0 = row0 & 2047;
    #pragma unroll
    for (int it=0; it<2*CT; it++){
      const int cl = it*(NWV*8) + (tid>>3);
      const int t8 = (tid&7)*8;
      s8v o = *(const s8v*)&Lt[cl*72 + t8];
      const int cr = cb0 + cl - vcol0;      // 0..127 within V
      *(s8v*)(vtb + ((size_t)((b*4 + (cr>>5))*32 + (cr&31)))*2048 + t0 + t8) = o;
    }
  }
}

// ---------------- fused F2 GEMM: [N x 512] @ [512 x 128] + epilogue ----------------
// 512 thr = 8 waves, each block owns 64 rows x ALL 128 cols (full row -> can fuse row ops).
// MODE 0: + residual(h1p) + LayerNorm -> vAp dual-plane
// MODE 1: + output head (tile @ Wo + bo) -> out
template<int MODE>
__global__ __launch_bounds__(512) void gemm_f2(
    const unsigned short* __restrict__ A,    // mid bf16, lda=512, single plane
    const short* __restrict__ wt, int NTK,   // dual-plane W [128][512]
    const float* __restrict__ bias,          // f2b [128]
    const unsigned short* __restrict__ resid,// MODE0: h1p dual-plane
    const float* __restrict__ g, const float* __restrict__ bt,
    unsigned short* __restrict__ outp,       // MODE0: vAp dual-plane
    const float* __restrict__ Wo, const float* __restrict__ bo,
    float* __restrict__ outhead){            // MODE1: out [N x 32]
  __shared__ short As[2][64*40];
  __shared__ float Lf[64*132];
  __shared__ float Ws2[128*32];
  const int tid  = threadIdx.x;
  const int w    = tid >> 6;
  const int lane = tid & 63;
  const int col  = lane & 15;
  const int quad = lane >> 4;
  const int row0 = blockIdx.x * 64;
  const int cg   = w*16 + col;            // 0..127

  if (MODE == 1){
    for (int idx = tid; idx < 128*32; idx += 512) Ws2[idx] = Wo[idx];
  }

  f4v acc[4];
  #pragma unroll
  for (int i=0;i<4;i++) acc[i] = (f4v){0.f,0.f,0.f,0.f};

  const int ar = tid >> 3, ac = (tid & 7)*4;
  const unsigned short* abase = A + (size_t)(row0 + ar)*512;
  s4v pa = *(const s4v*)(abase + ac);
  const short* wb = wt + (size_t)cg*512 + quad*8;

  for (int i=0;i<16;i++){
    const int buf = i & 1;
    *(s4v*)&As[buf][ar*40 + ac] = pa;
    __syncthreads();
    if (i+1 < 16) pa = *(const s4v*)(abase + (i+1)*32 + ac);
    s8v bh = *(const s8v*)(wb + i*32);
    s8v bl = *(const s8v*)(wb + i*32 + NTK);
    #pragma unroll
    for (int rt=0;rt<4;rt++){
      s8v ah = *(const s8v*)&As[buf][(rt*16 + col)*40 + quad*8];
      acc[rt] = __builtin_amdgcn_mfma_f32_16x16x32_bf16(ah, bh, acc[rt], 0, 0, 0);
      acc[rt] = __builtin_amdgcn_mfma_f32_16x16x32_bf16(ah, bl, acc[rt], 0, 0, 0);
    }
  }

  // stage tile (with bias) to LDS
  const float bv = bias[cg];
  #pragma unroll
  for (int rt=0;rt<4;rt++){
    #pragma unroll
    for (int r=0;r<4;r++){
      const int row = rt*16 + quad*4 + r;
      Lf[row*132 + cg] = acc[rt][r] + bv;
    }
  }
  __syncthreads();

  if (MODE == 0){
    // residual + LayerNorm, 8 rows per wave
    for (int rr=0; rr<8; rr++){
      const int row = w*8 + rr;
      const size_t gbase = (size_t)(row0 + row)*EMB;
      float x0 = Lf[row*132 + lane]
               + bf2f(resid[gbase+lane])    + bf2f(resid[gbase+lane+APLANE]);
      float x1 = Lf[row*132 + lane + 64]
               + bf2f(resid[gbase+lane+64]) + bf2f(resid[gbase+lane+64+APLANE]);
      float s  = x0 + x1;
      float s2 = x0*x0 + x1*x1;
      #pragma unroll
      for (int off=1; off<64; off<<=1){
        s  += __shfl_xor(s,  off);
        s2 += __shfl_xor(s2, off);
      }
      float mean = s * (1.f/128.f);
      float var  = s2 * (1.f/128.f) - mean*mean;
      float rstd = rsqrtf(var + 1e-5f);
      float y0 = (x0-mean)*rstd*g[lane]    + bt[lane];
      float y1 = (x1-mean)*rstd*g[lane+64] + bt[lane+64];
      unsigned short h0b = f2bf(y0), h1b = f2bf(y1);
      outp[gbase+lane]             = h0b;
      outp[gbase+lane+64]          = h1b;
      outp[gbase+lane+APLANE]      = f2bf(y0 - bf2f(h0b));
      outp[gbase+lane+64+APLANE]   = f2bf(y1 - bf2f(h1b));
    }
  } else {
    // output head: out[row, c] = sum_k Lf[row][k] * Wo[k][c] + bo[c]
    const int row = tid >> 3, c0 = (tid & 7)*4;
    f4v a4;
    #pragma unroll
    for (int j=0;j<4;j++) a4[j] = bo[c0+j];
    #pragma unroll 16
    for (int k=0;k<128;k++){
      const float av = Lf[row*132 + k];
      #pragma unroll
      for (int j=0;j<4;j++) a4[j] = fmaf(av, Ws2[k*32 + c0 + j], a4[j]);
    }
    float* op = outhead + (size_t)(row0 + row)*OUTD + c0;
    #pragma unroll
    for (int j=0;j<4;j++) op[j] = a4[j];
  }
}

// ---------------- flash attention v5: 32x32 MFMA, swapped QK^T, in-register softmax->PV ----------------
#define KSTR 40
#define VSTR 72
__device__ __forceinline__ int kswz(int row, int c){ return (row*KSTR + c) ^ (((row>>3)&3)<<3); }
__device__ __forceinline__ int vswz(int row, int c){ return (row*VSTR + c) ^ (((row>>3)&3)<<3); }

__global__ __launch_bounds__(256, 4) void flash5(const unsigned short* __restrict__ Qb,
                                                 const unsigned short* __restrict__ Kb,
                                                 const unsigned short* __restrict__ Vtb,
                                                 float* __restrict__ O, float* __restrict__ L,
                                                 int mode){
  __shared__ short Kt[64*KSTR];
  __shared__ short Vt[32*VSTR];
  const int tid  = threadIdx.x;
  const int w    = tid >> 6;
  const int lane = tid & 63;
  const int q31  = lane & 31;
  const int hi   = lane >> 5;
  const int bh = blockIdx.y;
  const int b = bh >> 2, h = bh & 3;
  const int par = blockIdx.z;
  float* Op = O + (size_t)par*NROWS*EMB;
  float* Lp = L + (size_t)par*NROWS*NH;
  const int kr = tid >> 2, kc8 = (tid & 3)*8;   // K staging: 64 rows x 32 d
  const int vd = tid >> 3, vk8 = (tid & 7)*8;   // V staging: 32 d x 64 k

  for (int pass = 0; pass < 2; pass++){
    const int qt = pass ? (int)blockIdx.x : (15 - (int)blockIdx.x);  // heavy first
    const int qbase = qt*128;
    const int qrow  = qbase + w*32 + q31;
    const int jtmax = 2*qt + 1;

    s8v qB0 = *(const s8v*)(Qb + (size_t)(b*TSEQ + qrow)*EMB + h*DH + hi*8);
    s8v qB1 = *(const s8v*)(Qb + (size_t)(b*TSEQ + qrow)*EMB + h*DH + 16 + hi*8);
    f16v o;
    #pragma unroll
    for (int r=0;r<16;r++) o[r] = 0.f;
    float lr = 0.f;

    if (par <= jtmax){
      s8v ka = *(const s8v*)(Kb + (size_t)(b*TSEQ + par*64 + kr)*EMB + h*DH + kc8);
      s8v va = *(const s8v*)(Vtb + ((size_t)bh*32 + vd)*TSEQ + par*64 + vk8);
      for (int jt = par; jt <= jtmax; jt += NPAR){
        __syncthreads();
        *(s8v*)&Kt[kswz(kr, kc8)] = ka;
        *(s8v*)&Vt[vswz(vd, vk8)] = va;
        __syncthreads();
        if (jt + NPAR <= jtmax){
          ka = *(const s8v*)(Kb + (size_t)(b*TSEQ + (jt+NPAR)*64 + kr)*EMB + h*DH + kc8);
          va = *(const s8v*)(Vtb + ((size_t)bh*32 + vd)*TSEQ + (jt+NPAR)*64 + vk8);
        }
        const bool domask = (jt >= 2*qt);
        #pragma unroll
        for (int kt=0;kt<2;kt++){
          f16v s;
          #pragma unroll
          for (int r=0;r<16;r++) s[r] = 0.f;
          {
            s8v kf0 = *(const s8v*)&Kt[kswz(kt*32 + q31, hi*8)];
            s = __builtin_amdgcn_mfma_f32_32x32x16_bf16(kf0, qB0, s, 0, 0, 0);
            s8v kf1 = *(const s8v*)&Kt[kswz(kt*32 + q31, 16 + hi*8)];
            s = __builtin_amdgcn_mfma_f32_32x32x16_bf16(kf1, qB1, s, 0, 0, 0);
          }
          if (domask){
            #pragma unroll
            for (int r=0;r<16;r++){
              const int jg = jt*64 + kt*32 + (r&3) + 8*(r>>2) + 4*hi;
              const bool ok = (mode==0) ? (jg <= qrow) : ((jg < qrow) || (qrow==0 && jg==0));
              s[r] = ok ? s[r] : -1e30f;
            }
          }
          #pragma unroll
          for (int r=0;r<16;r++){ float pv = exp2fast(s[r]); s[r] = pv; lr += pv; }
          unsigned P2[4][2];
          #pragma unroll
          for (int m=0;m<4;m++){
            asm("v_cvt_pk_bf16_f32 %0, %1, %2" : "=v"(P2[m][0]) : "v"(s[4*m+0]), "v"(s[4*m+1]));
            asm("v_cvt_pk_bf16_f32 %0, %1, %2" : "=v"(P2[m][1]) : "v"(s[4*m+2]), "v"(s[4*m+3]));
          }
          #pragma unroll
          for (int kcl=0;kcl<2;kcl++){
            const unsigned own0 = hi ? P2[2*kcl+1][0] : P2[2*kcl][0];
            const unsigned own1 = hi ? P2[2*kcl+1][1] : P2[2*kcl][1];
            const unsigned inv0 = hi ? P2[2*kcl][0]   : P2[2*kcl+1][0];
            const unsigned inv1 = hi ? P2[2*kcl][1]   : P2[2*kcl+1][1];
            const unsigned sx0 = (unsigned)__shfl_xor((int)inv0, 32);
            const unsigned sx1 = (unsigned)__shfl_xor((int)inv1, 32);
            u4v au;
            au[0] = hi ? sx0 : own0;  au[1] = hi ? sx1 : own1;
            au[2] = hi ? own0 : sx0;  au[3] = hi ? own1 : sx1;
            s8v af = __builtin_bit_cast(s8v, au);
            s8v vf = *(const s8v*)&Vt[vswz(q31, kt*32 + kcl*16 + hi*8)];
            o = __builtin_amdgcn_mfma_f32_32x32x16_bf16(af, vf, o, 0, 0, 0);
          }
        }
      }
    }
    const float lt = lr + __shfl_xor(lr, 32);
    #pragma unroll
    for (int r=0;r<16;r++){
      const int ql = (r&3) + 8*(r>>2) + 4*hi;
      Op[(size_t)(b*TSEQ + qbase + w*32 + ql)*EMB + h*DH + q31] = o[r];
    }
    if (hi == 0) Lp[(size_t)(b*TSEQ + qrow)*NH + h] = lt;
  }
}

// ---------------- combine + residual + LayerNorm (layer A) -> dual-plane bf16 ----------------
__global__ __launch_bounds__(256) void combine_ln(const float* __restrict__ O, const float* __restrict__ L,
                                                  const float* __restrict__ Vf,
                                                  const float* __restrict__ g, const float* __restrict__ bt,
                                                  unsigned short* __restrict__ outp){
  const int row = blockIdx.x*4 + (threadIdx.x >> 6);
  const int tid = threadIdx.x & 63;
  const size_t base = (size_t)row*EMB;
  const int h0 = tid >> 5, h1i = 2 + (tid >> 5);
  float la = 0.f, lb = 0.f, s0 = 0.f, s1 = 0.f;
  #pragma unroll
  for (int p=0;p<NPAR;p++){
    la += L[(size_t)p*NROWS*NH + (size_t)row*NH + h0];
    lb += L[(size_t)p*NROWS*NH + (size_t)row*NH + h1i];
    s0 += O[(size_t)p*NROWS*EMB + base + tid];
    s1 += O[(size_t)p*NROWS*EMB + base + tid + 64];
  }
  float x0 = Vf[base+tid]    + s0/la;
  float x1 = Vf[base+tid+64] + s1/lb;
  float s  = x0 + x1;
  float s2 = x0*x0 + x1*x1;
  #pragma unroll
  for (int off=1; off<64; off<<=1){
    s  += __shfl_xor(s,  off);
    s2 += __shfl_xor(s2, off);
  }
  float mean = s * (1.f/128.f);
  float var  = s2 * (1.f/128.f) - mean*mean;
  float rstd = rsqrtf(var + 1e-5f);
  float y0 = (x0-mean)*rstd*g[tid]    + bt[tid];
  float y1 = (x1-mean)*rstd*g[tid+64] + bt[tid+64];
  unsigned short h0b = f2bf(y0), h1b = f2bf(y1);
  outp[base+tid]             = h0b;
  outp[base+tid+64]          = h1b;
  outp[base+tid+APLANE]      = f2bf(y0 - bf2f(h0b));
  outp[base+tid+64+APLANE]   = f2bf(y1 - bf2f(h1b));
}

extern "C" void kernel_launch(void* const* d_in, const int* in_sizes, int n_in,
                              void* d_out, int out_size, void* d_ws, size_t ws_size,
                              hipStream_t stream) {
  const float* kq    = (const float*)d_in[0];
  const float* v     = (const float*)d_in[1];
  const float* A_Wk  = (const float*)d_in[2];  const float* A_bk  = (const float*)d_in[3];
  const float* A_Wq  = (const float*)d_in[4];  const float* A_bq  = (const float*)d_in[5];
  const float* A_Wv  = (const float*)d_in[6];  const float* A_bv  = (const float*)d_in[7];
  const float* A_f1W = (const float*)d_in[8];  const float* A_f1b = (const float*)d_in[9];
  const float* A_f2W = (const float*)d_in[10]; const float* A_f2b = (const float*)d_in[11];
  const float* A_n1g = (const float*)d_in[12]; const float* A_n1b = (const float*)d_in[13];
  const float* A_n2g = (const float*)d_in[14]; const float* A_n2b = (const float*)d_in[15];
  const float* B_Wk  = (const float*)d_in[16]; const float* B_bk  = (const float*)d_in[17];
  const float* B_Wq  = (const float*)d_in[18]; const float* B_bq  = (const float*)d_in[19];
  const float* B_Wv  = (const float*)d_in[20]; const float* B_bv  = (const float*)d_in[21];
  const float* B_f1W = (const float*)d_in[22]; const float* B_f1b = (const float*)d_in[23];
  const float* B_f2W = (const float*)d_in[24]; const float* B_f2b = (const float*)d_in[25];
  const float* out_W = (const float*)d_in[26]; const float* out_b = (const float*)d_in[27];
  float* out = (float*)d_out;
  (void)in_sizes; (void)n_in; (void)out_size; (void)ws_size;

  char* ws = (char*)d_ws;
  const size_t MB = 1024*1024;
  short* warena = (short*)ws;                              // 0-2 MB (1.32 MB used)
  unsigned short* Xs  = (unsigned short*)(ws + 2*MB);      // 2-10: X dual-plane bf16
  unsigned short* Qbf = (unsigned short*)(ws + 10*MB);     // 10-14
  unsigned short* Kbf = (unsigned short*)(ws + 14*MB);     // 14-18
  unsigned short* Vtb = (unsigned short*)(ws + 18*MB);     // 18-22
  float* Vf  = (float*)(ws + 22*MB);                       // 22-30
  float* Opar = (float*)(ws + 30*MB);                      // 30-62: 4 x 8MB split-K partial O
  float* Lpar = (float*)(ws + 62*MB);                      // 62-66: 4 x 1MB (256KB used) partial L
  unsigned short* h1p = (unsigned short*)(ws + 66*MB);     // 66-74: h1 dual-plane (layer A)
  unsigned short* mid = (unsigned short*)(ws + 74*MB);     // 74-90: bf16 [N x 512]
  unsigned short* vAp = (unsigned short*)(ws + 90*MB);     // 90-98: vA dual-plane

  // ---- fused prep: xsplit + weight prep ----
  WPack p;
  const float* srcs[10] = {A_Wq,A_Wk,A_Wv,A_f1W,A_f2W,B_Wq,B_Wk,B_Wv,B_f1W,B_f2W};
  int kn[10]     = {16384,16384,16384,65536,65536,8192,8192,16384,65536,65536};
  int nsh[10]    = {7,7,7,9,7,7,7,7,9,7};
  int off[10]    = {0,0,0,98304,229376,360448,360448,393216,425984,557056};
  int ntk[10]    = {49152,49152,49152,65536,65536,16384,16384,16384,65536,65536};
  int rowoff[10] = {0,128,256,0,0,0,128,0,0,0};
  int nblk = 0;
  for (int i=0;i<10;i++){
    p.src[i]=srcs[i]; p.kn[i]=kn[i]; p.nsh[i]=nsh[i];
    p.off[i]=off[i]; p.ntk[i]=ntk[i]; p.rowoff[i]=rowoff[i];
    nblk += kn[i] >> 8;
  }
  prep<<<(NROWS*EMB/256) + nblk, 256, 0, stream>>>(p, warena, kq, v, Xs);

  GOuts oQKVA = {{A_bq,A_bk,A_bv},{nullptr,nullptr,Vf},{Qbf,Kbf,nullptr},{LOG2E,1.f,1.f}};
  GOuts oF1A  = {{A_f1b,nullptr,nullptr},{nullptr,nullptr,nullptr},{mid,nullptr,nullptr},{1.f,1.f,1.f}};
  GOuts oQKB  = {{B_bq,B_bk,nullptr},{nullptr,nullptr,nullptr},{Qbf,Kbf,nullptr},{LOG2E,1.f,1.f}};
  GOuts oVB   = {{B_bv,nullptr,nullptr},{nullptr,nullptr,nullptr},{nullptr,nullptr,nullptr},{1.f,1.f,1.f}};
  GOuts oF1B  = {{B_f1b,nullptr,nullptr},{nullptr,nullptr,nullptr},{mid,nullptr,nullptr},{1.f,1.f,1.f}};

  // ---- Layer A ----
  gemm2<2,4,4,0><<<dim3(256,3), 256, 0, stream>>>(Xs, APLANE, 128, 128, warena + 0, 49152, oQKVA, 384, 3, 0, Vtb, 256, nullptr, nullptr);
  flash5<<<dim3(8,32,NPAR), 256, 0, stream>>>(Qbf, Kbf, Vtb, Opar, Lpar, 0);
  combine_ln<<<NROWS/4, 256, 0, stream>>>(Opar, Lpar, Vf, A_n1g, A_n1b, h1p);
  gemm2<2,8,4,0><<<dim3(256,2), 512, 0, stream>>>(h1p, APLANE, 128, 128, warena + 98304, 65536, oF1A, 512, 1, 1, nullptr, 0, nullptr, nullptr);
  gemm_f2<0><<<256, 512, 0, stream>>>(mid, warena + 229376, 65536, A_f2b,
                                      h1p, A_n2g, A_n2b, vAp, nullptr, nullptr, nullptr);

  // ---- Layer B ----
  gemm2<2,8,2,0><<<dim3(256,1), 512, 0, stream>>>(Xs, APLANE, 128, 64, warena + 360448, 16384, oQKB, 256, 2, 0, nullptr, 0, nullptr, nullptr);
  gemm2<1,8,4,0><<<dim3(256,1), 512, 0, stream>>>(vAp, APLANE, 128, 128, warena + 393216, 16384, oVB, 128, 1, 0, Vtb, 0, nullptr, nullptr);
  flash5<<<dim3(8,32,NPAR), 256, 0, stream>>>(Qbf, Kbf, Vtb, Opar, Lpar, 1);
  // F1B with fused split-K combine in the A-stage (combine_b kernel + h1p round-trip eliminated)
  gemm2<2,8,4,1><<<dim3(256,2), 512, 0, stream>>>(nullptr, 1, 128, 128, warena + 425984, 65536, oF1B, 512, 1, 1, nullptr, 0, Opar, Lpar);
  gemm_f2<1><<<256, 512, 0, stream>>>(mid, warena + 557056, 65536, B_f2b,
                                      nullptr, nullptr, nullptr, nullptr, out_W, out_b, out);
}